// Round 8
// baseline (232.377 us; speedup 1.0000x reference)
//
#include <hip/hip_runtime.h>
#include <hip/hip_bf16.h>

typedef __attribute__((ext_vector_type(8))) short short8;
typedef __attribute__((ext_vector_type(4))) float f32x4;
typedef __attribute__((ext_vector_type(16))) float f32x16;

#define BATCH 4
#define TLEN 4096
#define CDIM 1024
#define HSD 128
#define MROWS (BATCH*TLEN)

// 1/sqrt(128) * log2(e): fold into Q so softmax runs in exp2 domain
#define QSCALE 0.12751744f

__device__ __forceinline__ unsigned short f2bf(float f){
    unsigned u = __builtin_bit_cast(unsigned, f);
    u = (u + 0x7FFFu + ((u >> 16) & 1u)) >> 16;
    return (unsigned short)u;
}
__device__ __forceinline__ unsigned pkbf(float a, float b){
    unsigned ua = (__builtin_bit_cast(unsigned, a) + 0x8000u) >> 16;
    unsigned ub = (__builtin_bit_cast(unsigned, b) + 0x8000u) & 0xFFFF0000u;
    return ua | ub;
}

// ---------------- kernel 1: W (C,HS) fp32 -> Wt (3,HS,C) bf16, LDS transpose ----------------
__global__ void prep_w_k(const float* __restrict__ Wq, const float* __restrict__ Wk,
                         const float* __restrict__ Wv, unsigned short* __restrict__ Wt){
    __shared__ float tile[32][33];
    const int w = blockIdx.z;
    const float* W = (w == 0) ? Wq : ((w == 1) ? Wk : Wv);
    const int c0 = blockIdx.x * 32, h0 = blockIdx.y * 32;
    const int lx = threadIdx.x & 31, ly = threadIdx.x >> 5;   // ly 0..7
#pragma unroll
    for (int i = 0; i < 4; i++){
        int c = c0 + ly + i * 8;
        tile[ly + i * 8][lx] = W[(size_t)c * HSD + h0 + lx];   // coalesced read over h
    }
    __syncthreads();
#pragma unroll
    for (int i = 0; i < 4; i++){
        int h = h0 + ly + i * 8;
        Wt[((size_t)w * HSD + h) * CDIM + c0 + lx] = f2bf(tile[lx][ly + i * 8]); // coalesced write over c
    }
}

// ---------------- kernel 2: fused QKV projection GEMM (x read ONCE) ----------------
__device__ __forceinline__ void stage_wb(unsigned short* buf, const unsigned short* g, int tid){
#pragma unroll
    for (int i = 0; i < 3; i++){
        int c = i * 512 + tid;              // 1536 chunks: 384 rows x 4 x 16B
        int row = c >> 2, kp = c & 3;
        int swz = (row & 3) ^ ((row >> 2) & 3);
        const unsigned short* gp = g + (size_t)row * CDIM + ((kp ^ swz) << 3);
        unsigned short* lp = buf + (c << 3);
        __builtin_amdgcn_global_load_lds((const __attribute__((address_space(1))) void*)gp,
                                         (__attribute__((address_space(3))) void*)lp, 16, 0, 0);
    }
}

__global__ __launch_bounds__(512) void proj_k(const float* __restrict__ x,
                                              const unsigned short* __restrict__ Wt,
                                              unsigned short* __restrict__ Qb,
                                              unsigned short* __restrict__ Kb,
                                              unsigned short* __restrict__ Vt){
    __shared__ unsigned short As[2][64 * 32];     // 4 KB each
    __shared__ unsigned short Bs[2][384 * 32];    // 24 KB each

    const int tid = threadIdx.x, lane = tid & 63, wave = tid >> 6;
    const int m = lane & 15, quad = lane >> 4;
    const int wr = wave & 1;        // t-half (32 rows)
    const int wc = wave >> 1;       // h-quarter (96 of 384 weight rows)
    const int rb = blockIdx.x * 64;

    const float* gA = x + (size_t)rb * CDIM;

    const int arow = tid >> 3, ach = tid & 7;
    const int asw = (arow & 3) ^ ((arow >> 2) & 3);
    const float* agp = gA + (size_t)arow * CDIM + ((((ach >> 1) ^ asw) << 3) + (ach & 1) * 4);
    unsigned short* asp0 = &As[0][arow * 32 + (ach << 2)];
    unsigned short* asp1 = &As[1][arow * 32 + (ach << 2)];

    f32x4 acc[6][2];
#pragma unroll
    for (int i = 0; i < 6; i++)
#pragma unroll
        for (int j = 0; j < 2; j++) acc[i][j] = (f32x4)0.f;

    stage_wb(&Bs[0][0], Wt, tid);
    {
        float4 a0 = *(const float4*)(agp);
        ushort4 o;
        o.x = f2bf(a0.x); o.y = f2bf(a0.y); o.z = f2bf(a0.z); o.w = f2bf(a0.w);
        *(ushort4*)asp0 = o;
    }
    __syncthreads();

    int cur = 0;
    for (int kc = 0; kc < CDIM / 32; ++kc){
        float4 a0n;
        if (kc + 1 < CDIM / 32){
            a0n = *(const float4*)(agp + (kc + 1) * 32);          // A first (oldest)
            stage_wb(&Bs[cur ^ 1][0], Wt + (kc + 1) * 32, tid);   // then 3 B loads
            asm volatile("s_waitcnt vmcnt(4)" ::: "memory");
        } else {
            asm volatile("s_waitcnt vmcnt(0)" ::: "memory");
        }
        __builtin_amdgcn_s_barrier();
        __builtin_amdgcn_sched_barrier(0);
        {
            short8 aF[6], bF[2];
#pragma unroll
            for (int i = 0; i < 6; i++){
                int ra = wc * 96 + i * 16 + m;
                int sa = (ra & 3) ^ ((ra >> 2) & 3);
                aF[i] = *(const short8*)&Bs[cur][ra * 32 + ((quad ^ sa) << 3)];
            }
#pragma unroll
            for (int j = 0; j < 2; j++){
                int rn = wr * 32 + j * 16 + m;
                int sb = (rn & 3) ^ ((rn >> 2) & 3);
                bF[j] = *(const short8*)&As[cur][rn * 32 + ((quad ^ sb) << 3)];
            }
#pragma unroll
            for (int i = 0; i < 6; i++)
#pragma unroll
                for (int j = 0; j < 2; j++)
                    acc[i][j] = __builtin_amdgcn_mfma_f32_16x16x32_bf16(aF[i], bF[j], acc[i][j], 0, 0, 0);
        }
        if (kc + 1 < CDIM / 32){
            ushort4 o;
            o.x = f2bf(a0n.x); o.y = f2bf(a0n.y); o.z = f2bf(a0n.z); o.w = f2bf(a0n.w);
            *(ushort4*)((cur == 0) ? asp1 : asp0) = o;
        }
        cur ^= 1;
    }
    __builtin_amdgcn_s_barrier();

    const int b = rb >> 12;
#pragma unroll
    for (int i = 0; i < 6; i++){
        const int hbase = wc * 96 + i * 16;
        const int type = hbase >> 7;              // 0=Q 1=K 2=V (16-row tiles never straddle)
        const int hp = hbase + quad * 4;
#pragma unroll
        for (int j = 0; j < 2; j++){
            const int t = rb + wr * 32 + j * 16 + m;
            if (type == 0){
                ushort4 v;
                v.x = f2bf(acc[i][j][0] * QSCALE); v.y = f2bf(acc[i][j][1] * QSCALE);
                v.z = f2bf(acc[i][j][2] * QSCALE); v.w = f2bf(acc[i][j][3] * QSCALE);
                *(ushort4*)(Qb + (size_t)t * HSD + hp) = v;
            } else if (type == 1){
                ushort4 v;
                v.x = f2bf(acc[i][j][0]); v.y = f2bf(acc[i][j][1]);
                v.z = f2bf(acc[i][j][2]); v.w = f2bf(acc[i][j][3]);
                *(ushort4*)(Kb + (size_t)t * HSD + (hp - 128)) = v;
            } else {
                const int tt = t & (TLEN - 1);
#pragma unroll
                for (int r = 0; r < 4; r++)
                    Vt[((size_t)b * HSD + (hp - 256 + r)) * TLEN + tt] = f2bf(acc[i][j][r]);
            }
        }
    }
}

// ---------------- kernel 3: causal flash attention, 32x32x16 MFMA, BARRIER-FREE ----------------
// grid (T/32, nseg, B), block 64 (ONE wave, 32 q-rows). No LDS, no barriers: the 32x32
// aK/bV fragments are lane-functions only, loaded straight from global (K/V are L2/L3
// resident, 8 MB total). ~2300 independent live waves, ~12 resident/CU at ~160 VGPR;
// latency hidden by TLP (the only mechanism rounds 0-2 showed operates here).
// V loads issue between QK and softmax so exp/pack covers their latency.
__global__ __launch_bounds__(64) void attn_k(const unsigned short* __restrict__ Qb,
                       const unsigned short* __restrict__ Kb,
                       const unsigned short* __restrict__ Vts,
                       float* __restrict__ Opart, float* __restrict__ lpart, int seglen){
    const int lane = threadIdx.x;
    const int col = lane & 31, half = lane >> 5;
    const int q0w = ((int)gridDim.x - 1 - (int)blockIdx.x) * 32;   // long blocks first
    const int seg = blockIdx.y, b = blockIdx.z;
    const int g0 = seg * seglen;
    if (g0 > q0w + 31) return;                    // no live (q,s) pair for this segment
    const int send = min(g0 + seglen, q0w + 32);
    const int nT = (send - g0) >> 5;

    const size_t rowg = (size_t)b * TLEN + q0w;
    const unsigned short* kbase = Kb + (size_t)b * TLEN * HSD;
    const unsigned short* vbase = Vts + (size_t)b * HSD * TLEN;

    // Q as B-operand fragments: lane holds Q[q0w+col][ks*16 + half*8 + j], j=0..7
    short8 aQ[8];
#pragma unroll
    for (int ks = 0; ks < 8; ks++)
        aQ[ks] = *(const short8*)(Qb + (rowg + col) * HSD + ks * 16 + half * 8);

    f32x16 accO[4];
#pragma unroll
    for (int i = 0; i < 4; i++) accO[i] = (f32x16)0.f;
    float lp = 0.f;

    for (int t = 0; t < nT; ++t){
        const int s0 = g0 + t * 32;
        // ---- K fragments from global: A-operand, lane holds K[s0+col][ks*16+half*8+j]
        const unsigned short* kp = kbase + (size_t)(s0 + col) * HSD + half * 8;
        short8 aK[8];
#pragma unroll
        for (int ks = 0; ks < 8; ks++)
            aK[ks] = *(const short8*)(kp + ks * 16);
        // ---- S^T = K Q^T : D[s][q], s = (r&3)+8*(r>>2)+4*half, q = col
        f32x16 S = (f32x16)0.f;
        __builtin_amdgcn_s_setprio(1);
#pragma unroll
        for (int ks = 0; ks < 8; ks++)
            S = __builtin_amdgcn_mfma_f32_32x32x16_bf16(aK[ks], aQ[ks], S, 0, 0, 0);
        __builtin_amdgcn_s_setprio(0);
        // ---- V fragments from global (issued now; exp/pack below covers their latency)
        // B-operand: lane holds V[s0 + ks*16 + half*8 + j][ht*32 + col]
        const unsigned short* vp = vbase + (size_t)col * TLEN + s0 + half * 8;
        short8 bV[8];
#pragma unroll
        for (int ks = 0; ks < 2; ks++)
#pragma unroll
            for (int ht = 0; ht < 4; ht++)
                bV[ks * 4 + ht] = *(const short8*)(vp + (size_t)(ht * 32) * TLEN + ks * 16);
        // ---- causal mask on boundary tile
        if (s0 + 31 > q0w){
            int qg = q0w + col;
#pragma unroll
            for (int r = 0; r < 16; r++){
                int sg = s0 + (r & 3) + 8 * (r >> 2) + 4 * half;
                if (sg > qg) S[r] = -1e30f;   // exp2 -> 0
            }
        }
        // ---- static softmax: P = exp2(S); lp accumulates this lane's 16 s-values
        float p[16];
#pragma unroll
        for (int r = 0; r < 16; r++) p[r] = exp2f(S[r]);
#pragma unroll
        for (int r = 0; r < 16; r++) lp += p[r];
        // ---- re-fragment P to 32x32x16 A-layout via cvt_pk + permlane32_swap
        short8 aP[2];
        {
            unsigned x1 = pkbf(p[0], p[1]), x2 = pkbf(p[2], p[3]);
            unsigned y1 = pkbf(p[4], p[5]), y2 = pkbf(p[6], p[7]);
            asm volatile("v_permlane32_swap_b32 %0, %1" : "+v"(x1), "+v"(y1));
            asm volatile("v_permlane32_swap_b32 %0, %1" : "+v"(x2), "+v"(y2));
            uint4 u; u.x = x1; u.y = x2; u.z = y1; u.w = y2;
            aP[0] = __builtin_bit_cast(short8, u);
            unsigned z1 = pkbf(p[8], p[9]),  z2 = pkbf(p[10], p[11]);
            unsigned w1 = pkbf(p[12], p[13]), w2 = pkbf(p[14], p[15]);
            asm volatile("v_permlane32_swap_b32 %0, %1" : "+v"(z1), "+v"(w1));
            asm volatile("v_permlane32_swap_b32 %0, %1" : "+v"(z2), "+v"(w2));
            uint4 u2; u2.x = z1; u2.y = z2; u2.z = w1; u2.w = w2;
            aP[1] = __builtin_bit_cast(short8, u2);
        }
        // ---- O += P V
        __builtin_amdgcn_s_setprio(1);
#pragma unroll
        for (int ks = 0; ks < 2; ks++)
#pragma unroll
            for (int ht = 0; ht < 4; ht++)
                accO[ht] = __builtin_amdgcn_mfma_f32_32x32x16_bf16(aP[ks], bV[ks * 4 + ht], accO[ht], 0, 0, 0);
        __builtin_amdgcn_s_setprio(0);
    }
    // ---- epilogue: combine half-lane partial sums; write per-segment partials
    lp += __shfl_xor(lp, 32, 64);
    if (lane < 32)
        lpart[(size_t)seg * MROWS + rowg + col] = lp;
    float* ob = Opart + (size_t)seg * MROWS * HSD;
#pragma unroll
    for (int ht = 0; ht < 4; ht++)
#pragma unroll
        for (int r = 0; r < 16; r++){
            int qrow = (r & 3) + 8 * (r >> 2) + 4 * half;
            ob[(rowg + qrow) * HSD + ht * 32 + col] = accO[ht][r];
        }
}

// ---------------- kernel 4: merge split-K partials (plain weighted sum) ----------------
__global__ void merge_k(const float* __restrict__ Opart, const float* __restrict__ lpart,
                        float* __restrict__ out, int nseg, int seglen){
    int idx = blockIdx.x * 256 + threadIdx.x;
    int row = idx >> 7;
    int t = row & (TLEN - 1);
    int nsv = min(nseg, (t | 31) / seglen + 1);   // q-tile granularity is 32 rows
    float L = 0.f, o = 0.f;
    for (int s = 0; s < nsv; s++){
        L += lpart[(size_t)s * MROWS + row];
        o += Opart[(size_t)s * MROWS * HSD + idx];
    }
    out[idx] = o / L;
}

extern "C" void kernel_launch(void* const* d_in, const int* in_sizes, int n_in,
                              void* d_out, int out_size, void* d_ws, size_t ws_size,
                              hipStream_t stream) {
    const float* x  = (const float*)d_in[0];
    const float* Wq = (const float*)d_in[1];
    const float* Wk = (const float*)d_in[2];
    const float* Wv = (const float*)d_in[3];
    float* out = (float*)d_out;
    char* w = (char*)d_ws;

    // layout: Wt@0, Qb@1M, Kb@5M, Vt@9M, lpart@13M, Opart@14M
    unsigned short* Wt = (unsigned short*)w;
    unsigned short* Qb = (unsigned short*)(w + ((size_t)1u  << 20));
    unsigned short* Kb = (unsigned short*)(w + ((size_t)5u  << 20));
    unsigned short* Vt = (unsigned short*)(w + ((size_t)9u  << 20));
    float* lpart       = (float*)(w + ((size_t)13u << 20));
    float* Opart;
    int nseg;
    const size_t segbytes = (size_t)MROWS * HSD * 4;   // 8.39 MB per segment
    if (ws_size >= ((size_t)14u << 20) + 8 * segbytes){
        nseg = 8;  Opart = (float*)(w + ((size_t)14u << 20));
    } else if (ws_size >= ((size_t)14u << 20) + 4 * segbytes){
        nseg = 4;  Opart = (float*)(w + ((size_t)14u << 20));
    } else {
        nseg = 1;  Opart = out;   // merge then normalizes in place
    }
    const int seglen = TLEN / nseg;

    prep_w_k<<<dim3(CDIM / 32, HSD / 32, 3), 256, 0, stream>>>(Wq, Wk, Wv, Wt);
    proj_k<<<dim3(MROWS / 64), 512, 0, stream>>>(x, Wt, Qb, Kb, Vt);
    attn_k<<<dim3(TLEN / 32, nseg, BATCH), 64, 0, stream>>>(Qb, Kb, Vt, Opart, lpart, seglen);
    merge_k<<<(MROWS * HSD) / 256, 256, 0, stream>>>(Opart, lpart, out, nseg, seglen);
}

// Round 9
// 205.856 us; speedup vs baseline: 1.1288x; 1.1288x over previous
//
#include <hip/hip_runtime.h>
#include <hip/hip_bf16.h>

typedef __attribute__((ext_vector_type(8))) short short8;
typedef __attribute__((ext_vector_type(4))) float f32x4;
typedef __attribute__((ext_vector_type(16))) float f32x16;

#define BATCH 4
#define TLEN 4096
#define CDIM 1024
#define HSD 128
#define MROWS (BATCH*TLEN)

// 1/sqrt(128) * log2(e): fold into Q so softmax runs in exp2 domain
#define QSCALE 0.12751744f

__device__ __forceinline__ unsigned short f2bf(float f){
    unsigned u = __builtin_bit_cast(unsigned, f);
    u = (u + 0x7FFFu + ((u >> 16) & 1u)) >> 16;
    return (unsigned short)u;
}
__device__ __forceinline__ unsigned pkbf(float a, float b){
    unsigned ua = (__builtin_bit_cast(unsigned, a) + 0x8000u) >> 16;
    unsigned ub = (__builtin_bit_cast(unsigned, b) + 0x8000u) & 0xFFFF0000u;
    return ua | ub;
}

// ---------------- kernel 1: W (C,HS) fp32 -> Wt (3,HS,C) bf16, LDS transpose ----------------
__global__ void prep_w_k(const float* __restrict__ Wq, const float* __restrict__ Wk,
                         const float* __restrict__ Wv, unsigned short* __restrict__ Wt){
    __shared__ float tile[32][33];
    const int w = blockIdx.z;
    const float* W = (w == 0) ? Wq : ((w == 1) ? Wk : Wv);
    const int c0 = blockIdx.x * 32, h0 = blockIdx.y * 32;
    const int lx = threadIdx.x & 31, ly = threadIdx.x >> 5;   // ly 0..7
#pragma unroll
    for (int i = 0; i < 4; i++){
        int c = c0 + ly + i * 8;
        tile[ly + i * 8][lx] = W[(size_t)c * HSD + h0 + lx];   // coalesced read over h
    }
    __syncthreads();
#pragma unroll
    for (int i = 0; i < 4; i++){
        int h = h0 + ly + i * 8;
        Wt[((size_t)w * HSD + h) * CDIM + c0 + lx] = f2bf(tile[lx][ly + i * 8]); // coalesced write over c
    }
}

// ---------------- kernel 2: fused QKV projection GEMM (x read ONCE) ----------------
__device__ __forceinline__ void stage_wb(unsigned short* buf, const unsigned short* g, int tid){
#pragma unroll
    for (int i = 0; i < 3; i++){
        int c = i * 512 + tid;              // 1536 chunks: 384 rows x 4 x 16B
        int row = c >> 2, kp = c & 3;
        int swz = (row & 3) ^ ((row >> 2) & 3);
        const unsigned short* gp = g + (size_t)row * CDIM + ((kp ^ swz) << 3);
        unsigned short* lp = buf + (c << 3);
        __builtin_amdgcn_global_load_lds((const __attribute__((address_space(1))) void*)gp,
                                         (__attribute__((address_space(3))) void*)lp, 16, 0, 0);
    }
}

__global__ __launch_bounds__(512) void proj_k(const float* __restrict__ x,
                                              const unsigned short* __restrict__ Wt,
                                              unsigned short* __restrict__ Qb,
                                              unsigned short* __restrict__ Kb,
                                              unsigned short* __restrict__ Vt){
    __shared__ unsigned short As[2][64 * 32];     // 4 KB each
    __shared__ unsigned short Bs[2][384 * 32];    // 24 KB each

    const int tid = threadIdx.x, lane = tid & 63, wave = tid >> 6;
    const int m = lane & 15, quad = lane >> 4;
    const int wr = wave & 1;        // t-half (32 rows)
    const int wc = wave >> 1;       // h-quarter (96 of 384 weight rows)
    const int rb = blockIdx.x * 64;

    const float* gA = x + (size_t)rb * CDIM;

    const int arow = tid >> 3, ach = tid & 7;
    const int asw = (arow & 3) ^ ((arow >> 2) & 3);
    const float* agp = gA + (size_t)arow * CDIM + ((((ach >> 1) ^ asw) << 3) + (ach & 1) * 4);
    unsigned short* asp0 = &As[0][arow * 32 + (ach << 2)];
    unsigned short* asp1 = &As[1][arow * 32 + (ach << 2)];

    f32x4 acc[6][2];
#pragma unroll
    for (int i = 0; i < 6; i++)
#pragma unroll
        for (int j = 0; j < 2; j++) acc[i][j] = (f32x4)0.f;

    stage_wb(&Bs[0][0], Wt, tid);
    {
        float4 a0 = *(const float4*)(agp);
        ushort4 o;
        o.x = f2bf(a0.x); o.y = f2bf(a0.y); o.z = f2bf(a0.z); o.w = f2bf(a0.w);
        *(ushort4*)asp0 = o;
    }
    __syncthreads();

    int cur = 0;
    for (int kc = 0; kc < CDIM / 32; ++kc){
        float4 a0n;
        if (kc + 1 < CDIM / 32){
            a0n = *(const float4*)(agp + (kc + 1) * 32);          // A first (oldest)
            stage_wb(&Bs[cur ^ 1][0], Wt + (kc + 1) * 32, tid);   // then 3 B loads
            asm volatile("s_waitcnt vmcnt(4)" ::: "memory");
        } else {
            asm volatile("s_waitcnt vmcnt(0)" ::: "memory");
        }
        __builtin_amdgcn_s_barrier();
        __builtin_amdgcn_sched_barrier(0);
        {
            short8 aF[6], bF[2];
#pragma unroll
            for (int i = 0; i < 6; i++){
                int ra = wc * 96 + i * 16 + m;
                int sa = (ra & 3) ^ ((ra >> 2) & 3);
                aF[i] = *(const short8*)&Bs[cur][ra * 32 + ((quad ^ sa) << 3)];
            }
#pragma unroll
            for (int j = 0; j < 2; j++){
                int rn = wr * 32 + j * 16 + m;
                int sb = (rn & 3) ^ ((rn >> 2) & 3);
                bF[j] = *(const short8*)&As[cur][rn * 32 + ((quad ^ sb) << 3)];
            }
#pragma unroll
            for (int i = 0; i < 6; i++)
#pragma unroll
                for (int j = 0; j < 2; j++)
                    acc[i][j] = __builtin_amdgcn_mfma_f32_16x16x32_bf16(aF[i], bF[j], acc[i][j], 0, 0, 0);
        }
        if (kc + 1 < CDIM / 32){
            ushort4 o;
            o.x = f2bf(a0n.x); o.y = f2bf(a0n.y); o.z = f2bf(a0n.z); o.w = f2bf(a0n.w);
            *(ushort4*)((cur == 0) ? asp1 : asp0) = o;
        }
        cur ^= 1;
    }
    __builtin_amdgcn_s_barrier();

    const int b = rb >> 12;
#pragma unroll
    for (int i = 0; i < 6; i++){
        const int hbase = wc * 96 + i * 16;
        const int type = hbase >> 7;              // 0=Q 1=K 2=V (16-row tiles never straddle)
        const int hp = hbase + quad * 4;
#pragma unroll
        for (int j = 0; j < 2; j++){
            const int t = rb + wr * 32 + j * 16 + m;
            if (type == 0){
                ushort4 v;
                v.x = f2bf(acc[i][j][0] * QSCALE); v.y = f2bf(acc[i][j][1] * QSCALE);
                v.z = f2bf(acc[i][j][2] * QSCALE); v.w = f2bf(acc[i][j][3] * QSCALE);
                *(ushort4*)(Qb + (size_t)t * HSD + hp) = v;
            } else if (type == 1){
                ushort4 v;
                v.x = f2bf(acc[i][j][0]); v.y = f2bf(acc[i][j][1]);
                v.z = f2bf(acc[i][j][2]); v.w = f2bf(acc[i][j][3]);
                *(ushort4*)(Kb + (size_t)t * HSD + (hp - 128)) = v;
            } else {
                const int tt = t & (TLEN - 1);
#pragma unroll
                for (int r = 0; r < 4; r++)
                    Vt[((size_t)b * HSD + (hp - 256 + r)) * TLEN + tt] = f2bf(acc[i][j][r]);
            }
        }
    }
}

// ---------------- attention LDS staging (128-thread block, KVBLK=32) ----------------
__device__ __forceinline__ void stage_k_tile(unsigned short* buf, const unsigned short* g,
                                             int tid){
#pragma unroll
    for (int i = 0; i < 4; i++){
        int slot = i * 128 + tid;          // 512 slots: 32 rows x 16 chunks of 16B
        int row = slot >> 4;
        int ch  = slot & 15;
        const unsigned short* gp = g + row * 128 + ((ch ^ (row & 15)) << 3);
        unsigned short* lp = buf + (slot << 3);
        __builtin_amdgcn_global_load_lds((const __attribute__((address_space(1))) void*)gp,
                                         (__attribute__((address_space(3))) void*)lp, 16, 0, 0);
    }
}
// V tile repack (r7-proven): LDS row r (128 B) holds h = {2r, 2r+1}; logical chunk lc:
// lc>>2 = h-half, lc&3 = 16B s-block. Stored at LDS chunk lc ^ (r&7); read applies the
// same XOR -> b128 reads land ~2 lanes/bank (conflicts 3.17M -> 1.06M measured in r7).
__device__ __forceinline__ void stage_v_tile(unsigned short* buf, const unsigned short* g,
                                             int tid){
#pragma unroll
    for (int i = 0; i < 4; i++){
        int slot = i * 128 + tid;          // 512 slots: 64 rows x 8 chunks of 16B
        int row = slot >> 3;
        int ch  = slot & 7;
        int lc  = ch ^ (row & 7);          // logical chunk stored at this LDS slot
        const unsigned short* gp = g + (size_t)(2 * row + (lc >> 2)) * TLEN + ((lc & 3) << 3);
        unsigned short* lp = buf + (slot << 3);
        __builtin_amdgcn_global_load_lds((const __attribute__((address_space(1))) void*)gp,
                                         (__attribute__((address_space(3))) void*)lp, 16, 0, 0);
    }
}

// ---------------- kernel 3: causal flash attention, 32x32x16 MFMA ----------------
// grid (T/64, nseg, B), block 128 (2 waves x 32 q-rows). r5-proven datapath + r7 V-swizzle.
// 64-row blocks + nseg=16 -> 2176 live blocks (8.5/CU vs 5 LDS-capped resident slots):
// queue stays full through the causal tail; barriers sync only 2 waves. Natural VGPR
// (~90) -- NO min-waves launch bound (r4/r6 lesson). Counted-vmcnt double buffer.
__global__ __launch_bounds__(128) void attn_k(const unsigned short* __restrict__ Qb,
                       const unsigned short* __restrict__ Kb,
                       const unsigned short* __restrict__ Vts,
                       float* __restrict__ Opart, float* __restrict__ lpart, int seglen){
    __shared__ unsigned short Kt[2][32 * 128];   // 2 x 8 KB
    __shared__ unsigned short Vs[2][64 * 64];    // 2 x 8 KB (64 rows x 128 B)

    const int tid = threadIdx.x, lane = tid & 63, wave = tid >> 6;   // wave 0..1
    const int col = lane & 31, half = lane >> 5;
    const int q0 = ((int)gridDim.x - 1 - (int)blockIdx.x) * 64;   // long blocks first
    const int seg = blockIdx.y, b = blockIdx.z;
    const int g0 = seg * seglen;
    if (g0 >= q0 + 64) return;
    const int gend = min(g0 + seglen, q0 + 64);
    const int nT = (gend - g0) >> 5;

    const int q0w = q0 + wave * 32;              // wave owns q rows [q0w, q0w+32)
    const size_t rowg = (size_t)b * TLEN + q0w;

    const unsigned short* kbase = Kb + (size_t)b * TLEN * HSD;
    const unsigned short* vbase = Vts + (size_t)b * HSD * TLEN;

    // Q as B-operand fragments: lane holds Q[q0w+col][ks*16 + half*8 + j], j=0..7
    short8 aQ[8];
#pragma unroll
    for (int ks = 0; ks < 8; ks++)
        aQ[ks] = *(const short8*)(Qb + (rowg + col) * HSD + ks * 16 + half * 8);

    // prologue: stage tile 0 into buffer 0 (4 K + 4 V loads per thread)
    stage_k_tile(&Kt[0][0], kbase + (size_t)g0 * HSD, tid);
    stage_v_tile(&Vs[0][0], vbase + g0, tid);

    f32x16 accO[4];
#pragma unroll
    for (int i = 0; i < 4; i++) accO[i] = (f32x16)0.f;
    float lp = 0.f;                      // per-lane partial sum for q = col (half of s-range)

    // drain ONCE (aQ + tile0), then launder aQ so the compiler's waitcnt pass
    // never re-waits on these loads inside the pipelined loop.
    asm volatile("s_waitcnt vmcnt(0)" ::: "memory");
#pragma unroll
    for (int ks = 0; ks < 8; ks++){
        f32x4 q_ = __builtin_bit_cast(f32x4, aQ[ks]);
        asm volatile("" : "+v"(q_));
        aQ[ks] = __builtin_bit_cast(short8, q_);
    }

    int cur = 0;
    for (int t = 0; t < nT; ++t){
        const int s0 = g0 + t * 32;
        if (t + 1 < nT){                 // prefetch next tile into the other buffer
            stage_k_tile(&Kt[cur ^ 1][0], kbase + (size_t)(s0 + 32) * HSD, tid);
            stage_v_tile(&Vs[cur ^ 1][0], vbase + (s0 + 32), tid);
            // confirm tile t's 8 loads; leave tile t+1's 8 IN FLIGHT across the barriers
            asm volatile("s_waitcnt vmcnt(8)" ::: "memory");
        } else {
            asm volatile("s_waitcnt vmcnt(0)" ::: "memory");
        }
        __builtin_amdgcn_s_barrier();                 // both waves: tile t resident
        __builtin_amdgcn_sched_barrier(0);            // don't hoist ds_reads above barrier
        if (s0 <= q0w + 31){             // wave has at least one live (q,s) pair
            const unsigned short* Ktc = &Kt[cur][0];
            const unsigned short* Vsc = &Vs[cur][0];
            // ---- S^T = K Q^T : D[s][q], s = (r&3)+8*(r>>2)+4*half, q = col
            f32x16 S = (f32x16)0.f;
            __builtin_amdgcn_s_setprio(1);
#pragma unroll
            for (int ks = 0; ks < 8; ks++){
                short8 aK = *(const short8*)&Ktc[col * 128 + (((ks * 2 + half) ^ (col & 15)) << 3)];
                S = __builtin_amdgcn_mfma_f32_32x32x16_bf16(aK, aQ[ks], S, 0, 0, 0);
            }
            __builtin_amdgcn_s_setprio(0);
            if (s0 + 31 > q0w){          // boundary tile: causal mask s > q
                int qg = q0w + col;
#pragma unroll
                for (int r = 0; r < 16; r++){
                    int sg = s0 + (r & 3) + 8 * (r >> 2) + 4 * half;
                    if (sg > qg) S[r] = -1e30f;   // exp2 -> 0
                }
            }
            // ---- static softmax: P = exp2(S); lp accumulates this lane's 16 s-values
            float p[16];
#pragma unroll
            for (int r = 0; r < 16; r++) p[r] = exp2f(S[r]);
#pragma unroll
            for (int r = 0; r < 16; r++) lp += p[r];
            // ---- re-fragment P to 32x32x16 A-layout via cvt_pk + permlane32_swap
            short8 aP[2];
            {
                unsigned x1 = pkbf(p[0], p[1]), x2 = pkbf(p[2], p[3]);
                unsigned y1 = pkbf(p[4], p[5]), y2 = pkbf(p[6], p[7]);
                asm volatile("v_permlane32_swap_b32 %0, %1" : "+v"(x1), "+v"(y1));
                asm volatile("v_permlane32_swap_b32 %0, %1" : "+v"(x2), "+v"(y2));
                uint4 u; u.x = x1; u.y = x2; u.z = y1; u.w = y2;
                aP[0] = __builtin_bit_cast(short8, u);
                unsigned z1 = pkbf(p[8], p[9]),  z2 = pkbf(p[10], p[11]);
                unsigned w1 = pkbf(p[12], p[13]), w2 = pkbf(p[14], p[15]);
                asm volatile("v_permlane32_swap_b32 %0, %1" : "+v"(z1), "+v"(w1));
                asm volatile("v_permlane32_swap_b32 %0, %1" : "+v"(z2), "+v"(w2));
                uint4 u2; u2.x = z1; u2.y = z2; u2.z = w1; u2.w = w2;
                aP[1] = __builtin_bit_cast(short8, u2);
            }
            // ---- O += P V : B = V[s][h] from swizzled LDS, A = aP
            __builtin_amdgcn_s_setprio(1);
#pragma unroll
            for (int ks = 0; ks < 2; ks++){
#pragma unroll
                for (int ht = 0; ht < 4; ht++){
                    int h = ht * 32 + col;
                    int lc = ((h & 1) << 2) + ks * 2 + half;           // logical chunk
                    short8 bV = *(const short8*)&Vsc[(h >> 1) * 64 +
                            ((lc ^ ((h >> 1) & 7)) << 3)];
                    accO[ht] = __builtin_amdgcn_mfma_f32_32x32x16_bf16(aP[ks], bV, accO[ht], 0, 0, 0);
                }
            }
            __builtin_amdgcn_s_setprio(0);
        }
        __builtin_amdgcn_sched_barrier(0);            // don't sink ds_reads below barrier
        __builtin_amdgcn_s_barrier();                 // both waves done reading buf[cur]
        cur ^= 1;
    }
    // ---- epilogue: combine half-lane partial sums; write per-segment partials
    lp += __shfl_xor(lp, 32, 64);
    if (lane < 32)
        lpart[(size_t)seg * MROWS + rowg + col] = lp;
    float* ob = Opart + (size_t)seg * MROWS * HSD;
#pragma unroll
    for (int ht = 0; ht < 4; ht++)
#pragma unroll
        for (int r = 0; r < 16; r++){
            int qrow = (r & 3) + 8 * (r >> 2) + 4 * half;
            ob[(rowg + qrow) * HSD + ht * 32 + col] = accO[ht][r];
        }
}

// ---------------- kernel 4: merge split-K partials (float4 per thread) ----------------
__global__ void merge_k(const float* __restrict__ Opart, const float* __restrict__ lpart,
                        float* __restrict__ out, int nseg, int seglen){
    int idx = (blockIdx.x * 256 + threadIdx.x) * 4;
    int row = idx >> 7;
    int t = row & (TLEN - 1);
    int nsv = min(nseg, (t | 63) / seglen + 1);   // q-tile granularity is 64 rows
    float L = 0.f;
    float4 o = make_float4(0.f, 0.f, 0.f, 0.f);
    for (int s = 0; s < nsv; s++){
        L += lpart[(size_t)s * MROWS + row];
        float4 v = *(const float4*)&Opart[(size_t)s * MROWS * HSD + idx];
        o.x += v.x; o.y += v.y; o.z += v.z; o.w += v.w;
    }
    float inv = 1.f / L;
    o.x *= inv; o.y *= inv; o.z *= inv; o.w *= inv;
    *(float4*)&out[idx] = o;
}

extern "C" void kernel_launch(void* const* d_in, const int* in_sizes, int n_in,
                              void* d_out, int out_size, void* d_ws, size_t ws_size,
                              hipStream_t stream) {
    const float* x  = (const float*)d_in[0];
    const float* Wq = (const float*)d_in[1];
    const float* Wk = (const float*)d_in[2];
    const float* Wv = (const float*)d_in[3];
    float* out = (float*)d_out;
    char* w = (char*)d_ws;

    // layout: Wt@0, Qb@1M, Kb@5M, Vt@9M, lpart@13M (1MB = 16 segs), Opart@14M
    unsigned short* Wt = (unsigned short*)w;
    unsigned short* Qb = (unsigned short*)(w + ((size_t)1u  << 20));
    unsigned short* Kb = (unsigned short*)(w + ((size_t)5u  << 20));
    unsigned short* Vt = (unsigned short*)(w + ((size_t)9u  << 20));
    float* lpart       = (float*)(w + ((size_t)13u << 20));
    float* Opart;
    int nseg;
    const size_t segbytes = (size_t)MROWS * HSD * 4;   // 8.39 MB per segment
    if (ws_size >= ((size_t)14u << 20) + 16 * segbytes){
        nseg = 16; Opart = (float*)(w + ((size_t)14u << 20));
    } else if (ws_size >= ((size_t)14u << 20) + 8 * segbytes){
        nseg = 8;  Opart = (float*)(w + ((size_t)14u << 20));
    } else if (ws_size >= ((size_t)14u << 20) + 4 * segbytes){
        nseg = 4;  Opart = (float*)(w + ((size_t)14u << 20));
    } else {
        nseg = 1;  Opart = out;   // merge then normalizes in place
    }
    const int seglen = TLEN / nseg;

    prep_w_k<<<dim3(CDIM / 32, HSD / 32, 3), 256, 0, stream>>>(Wq, Wk, Wv, Wt);
    proj_k<<<dim3(MROWS / 64), 512, 0, stream>>>(x, Wt, Qb, Kb, Vt);
    attn_k<<<dim3(TLEN / 64, nseg, BATCH), 128, 0, stream>>>(Qb, Kb, Vt, Opart, lpart, seglen);
    merge_k<<<(MROWS * HSD) / 1024, 256, 0, stream>>>(Opart, lpart, out, nseg, seglen);
}